// Round 16
// baseline (152.947 us; speedup 1.0000x reference)
//
#include <hip/hip_runtime.h>
#include <cmath>

#define B 32
#define S 11
#define R 16
#define D 64
#define C 512
#define N 256   // R*R
#define LN_EPS 1e-3f

typedef unsigned short u16;
typedef unsigned int   u32;

using bf16x8 = __attribute__((ext_vector_type(8))) short;
using f32x4  = __attribute__((ext_vector_type(4))) float;

__device__ __forceinline__ float grid_coord(int i) {
    return -1.0f + (2.0f / 15.0f) * (float)i;
}

__device__ __forceinline__ u16 f2bf(float x) {
    union { float f; u32 u; } c; c.f = x;
    u32 r = c.u + 0x7fffu + ((c.u >> 16) & 1u);   // RNE
    return (u16)(r >> 16);
}

__device__ __forceinline__ float bf2f(u16 h) {
    union { u32 u; float f; } c; c.u = ((u32)h) << 16; return c.f;
}

// ==== PRE1: pos (0..255) | wprep (256..769) | init (770..857) | q0 (858..868)
__global__ __launch_bounds__(256) void pre1_kernel(
    const float* __restrict__ es_w1, const float* __restrict__ es_b1,
    const float* __restrict__ es_w2, const float* __restrict__ es_b2,
    const float* __restrict__ mi_w1, const float* __restrict__ mi_b1,
    const float* __restrict__ mi_w2, const float* __restrict__ mi_b2,
    const float* __restrict__ pk_w, const float* __restrict__ pk_b,
    const float* __restrict__ pv_w, const float* __restrict__ pv_b,
    const float* __restrict__ er_w, const float* __restrict__ er_b,
    const float* __restrict__ slots_mu, const float* __restrict__ s_p0,
    const float* __restrict__ s_s0,
    const float* __restrict__ ns_g, const float* __restrict__ ns_b,
    const float* __restrict__ pq_w, const float* __restrict__ pq_b,
    float* __restrict__ pos,
    u16* __restrict__ wkT, u16* __restrict__ wvT,
    float* __restrict__ ewp,
    float* __restrict__ slots0, float* __restrict__ sp0, float* __restrict__ ss0,
    float* __restrict__ w2q0, float* __restrict__ b2q0) {
    int bid = blockIdx.x;
    int t = threadIdx.x;
    if (bid < 256) {
        int n = bid;
        float g0 = grid_coord(n >> 4), g1 = grid_coord(n & 15);
        __shared__ float h[128];
        if (t < 128) {
            float hj = es_b1[t] + g0 * es_w1[t] + g1 * es_w1[128 + t];
            h[t] = fmaxf(hj, 0.0f);
        }
        __syncthreads();
        #pragma unroll
        for (int c0 = 0; c0 < C; c0 += 256) {
            int c = c0 + t;
            float acc = es_b2[c];
            #pragma unroll 16
            for (int jj = 0; jj < 128; ++jj) acc += h[jj] * es_w2[jj * C + c];
            pos[n * C + c] = acc;
        }
    } else if (bid < 770) {
        int idx = (bid - 256) * 256 + t;       // 0..131583
        if (idx < 131072) {
            int mat = idx >> 16;
            int i = idx & 65535;
            int c = i >> 7, j = i & 127;
            const float* pw = mat ? pv_w : pk_w;
            float acc = 0.f;
            #pragma unroll 8
            for (int k = 0; k < 64; ++k) acc += pw[c * 64 + k] * mi_w1[k * 128 + j];
            u16* dst = mat ? wvT : wkT;
            dst[j * 512 + c] = f2bf(acc);
        } else {
            int i = idx - 131072;              // 0..511
            int tt = i >> 7, j = i & 127;
            float acc = 0.f;
            if (tt == 0) {
                for (int k = 0; k < 64; ++k) acc += er_w[k] * mi_w1[k * 128 + j];
            } else if (tt == 1) {
                for (int k = 0; k < 64; ++k) acc += er_w[64 + k] * mi_w1[k * 128 + j];
            } else if (tt == 2) {
                for (int k = 0; k < 64; ++k) acc += (pk_b[k] + er_b[k]) * mi_w1[k * 128 + j];
                acc += mi_b1[j];
            } else {
                for (int k = 0; k < 64; ++k) acc += (pv_b[k] + er_b[k]) * mi_w1[k * 128 + j];
                acc += mi_b1[j];
            }
            ewp[i] = acc;
        }
    } else if (bid < 858) {
        int idx = (bid - 770) * 256 + t;
        slots0[idx] = slots_mu[idx % (S * D)];
        if (idx < B * S * 2) { sp0[idx] = s_p0[idx]; ss0[idx] = s_s0[idx]; }
    } else {
        // initial q -> w2q0/b2q0, per distinct slot s (slots identical over b)
        int s = bid - 858;                     // 0..10
        __shared__ float xlds[64], qs2[64];
        if (t < 64) {
            float x = slots_mu[s * D + t];
            float sum = x;
            #pragma unroll
            for (int off = 32; off > 0; off >>= 1) sum += __shfl_xor(sum, off);
            float m = sum * (1.0f / 64.0f);
            float dx = x - m;
            float vs = dx * dx;
            #pragma unroll
            for (int off = 32; off > 0; off >>= 1) vs += __shfl_xor(vs, off);
            float var = vs * (1.0f / 64.0f);
            xlds[t] = dx * rsqrtf(var + LN_EPS) * ns_g[t] + ns_b[t];
        }
        __syncthreads();
        if (t < 64) {
            float acc = pq_b[t];
            #pragma unroll 8
            for (int i = 0; i < 64; ++i) acc += xlds[i] * pq_w[i * D + t];
            qs2[t] = acc * 0.125f;
        }
        __syncthreads();
        if (t < 128) {
            float sacc = 0.f;
            #pragma unroll 8
            for (int dd = 0; dd < 64; ++dd) sacc += mi_w2[t * 64 + dd] * qs2[dd];
            w2q0[s * 128 + t] = sacc;
        }
        if (t < 64) {
            float v = mi_b2[t] * qs2[t];
            #pragma unroll
            for (int off = 32; off > 0; off >>= 1) v += __shfl_xor(v, off);
            if (t == 0) b2q0[s] = v;
        }
    }
}

// ============ PRE2: xw1 + iteration-0 logits (512 blocks) ===================
// GkT[b][j][n] fp32 (bbk folded), Gv16[b][n][j] bf16 (bbv folded), lgts0
__global__ __launch_bounds__(256) void pre2_kernel(
    const float* __restrict__ inputs, const float* __restrict__ pos,
    const u16* __restrict__ wkT,      // wvT at +65536
    const float* __restrict__ ewp,
    const float* __restrict__ s_p0, const float* __restrict__ s_s0,
    const float* __restrict__ w2q0, const float* __restrict__ b2q0,
    float* __restrict__ GkT, u16* __restrict__ Gv16,
    float* __restrict__ lgts0) {
    int bid = blockIdx.x;
    int t = threadIdx.x;
    int row0 = bid * 16;
    __shared__ u16 Xs[16 * 512];
    __shared__ float Gs[16 * 129];
    __shared__ float w2qs[11 * 132];
    __shared__ float e0s[128], e1s[128], bbk2[128], bbv2[128];
    if (t < 128) {
        e0s[t] = ewp[t]; e1s[t] = ewp[128 + t];
        bbk2[t] = ewp[256 + t]; bbv2[t] = ewp[384 + t];
    }
    for (int i = t; i < 11 * 128; i += 256)
        w2qs[(i >> 7) * 132 + (i & 127)] = w2q0[i];

    const float4* in4 = (const float4*)(inputs + (size_t)row0 * C);
    #pragma unroll
    for (int it = 0; it < 8; ++it) {
        int f = it * 256 + t;
        int lr = f >> 7;
        int c = (f & 127) * 4;
        float4 a = in4[f];
        float4 p = *(const float4*)(pos + (size_t)((row0 + lr) & (N - 1)) * C + c);
        u32 lo = (u32)f2bf(a.x + p.x) | ((u32)f2bf(a.y + p.y) << 16);
        u32 hi = (u32)f2bf(a.z + p.z) | ((u32)f2bf(a.w + p.w) << 16);
        int cs = c ^ ((lr & 7) << 3);
        *(uint2*)&Xs[lr * 512 + cs] = make_uint2(lo, hi);
    }
    __syncthreads();

    int w = t >> 6, l = t & 63;
    int l16 = l & 15, lq = l >> 4;
    int wc = w * 32;
    int b = row0 >> 8, nb = row0 & (N - 1);

    f32x4 acc[2][2];
    #pragma unroll
    for (int m = 0; m < 2; ++m)
        #pragma unroll
        for (int nt = 0; nt < 2; ++nt) acc[m][nt] = (f32x4){0.f, 0.f, 0.f, 0.f};

    for (int kt = 0; kt < 16; ++kt) {
        int k0 = kt * 32 + lq * 8;
        int ks = k0 ^ ((l16 & 7) << 3);
        bf16x8 xf = *(const bf16x8*)&Xs[l16 * 512 + ks];
        #pragma unroll
        for (int m = 0; m < 2; ++m) {
            const u16* Wm = wkT + (size_t)m * 65536;
            #pragma unroll
            for (int nt = 0; nt < 2; ++nt) {
                bf16x8 wf = *(const bf16x8*)(Wm + (size_t)(wc + nt * 16 + l16) * 512 + k0);
                acc[m][nt] = __builtin_amdgcn_mfma_f32_16x16x32_bf16(xf, wf, acc[m][nt], 0, 0, 0);
            }
        }
    }
    #pragma unroll
    for (int nt = 0; nt < 2; ++nt) {
        #pragma unroll
        for (int r = 0; r < 4; ++r) {
            int j = wc + nt * 16 + l16;
            int nl = lq * 4 + r;
            int n2 = nb + nl;
            float gk = acc[0][nt][r] + bbk2[j];
            GkT[((size_t)b * 128 + j) * 256 + n2] = gk;
            Gs[nl * 129 + j] = gk;
            Gv16[((size_t)b * 256 + n2) * 128 + j] = f2bf(acc[1][nt][r] + bbv2[j]);
        }
    }
    __syncthreads();

    // iteration-0 logits for this block's 16 n values x 11 slots
    if (t < 176) {
        int nl = t & 15, s = t >> 4;     // s in 0..10
        int n = nb + nl;
        int i2 = (b * S + s) * 2;
        float p0 = s_p0[i2 + 0], p1 = s_p0[i2 + 1];
        float q0 = s_s0[i2 + 0], q1 = s_s0[i2 + 1];
        float r0 = (grid_coord(n >> 4) - p0) / q0;
        float r1 = (grid_coord(n & 15) - p1) / q1;
        float accl = 0.f;
        #pragma unroll 8
        for (int j = 0; j < 128; ++j) {
            float h = Gs[nl * 129 + j] + r0 * e0s[j] + r1 * e1s[j];
            accl += fmaxf(h, 0.f) * w2qs[s * 132 + j];
        }
        lgts0[((size_t)b * S + s) * N + n] = accl + b2q0[s];
    }
}

// ============ UPKV: update(ind) [dup per half] + logits(ind+1), 512 thr =====
// Register-preloaded Gv/GkT streams: issued at entry, consumed after barriers.
__global__ __launch_bounds__(512, 4) void upkv_kernel(
    int ind,
    const float* __restrict__ lgts_r, float* __restrict__ lgts_w,
    const float* __restrict__ sp_r, const float* __restrict__ ss_r,
    float* __restrict__ sp_w, float* __restrict__ ss_w,
    const float* __restrict__ slots_r, float* __restrict__ slots_w,
    const float* __restrict__ GkT, const u16* __restrict__ Gv16,
    const float* __restrict__ ewp,
    const float* __restrict__ gru_k, const float* __restrict__ gru_rk,
    const float* __restrict__ gru_b,
    const float* __restrict__ nm_g, const float* __restrict__ nm_b,
    const float* __restrict__ mlp_w1, const float* __restrict__ mlp_b1,
    const float* __restrict__ mlp_w2, const float* __restrict__ mlp_b2,
    const float* __restrict__ ns_g, const float* __restrict__ ns_b,
    const float* __restrict__ pq_w, const float* __restrict__ pq_b,
    const float* __restrict__ mi_w2, const float* __restrict__ mi_b2,
    float* __restrict__ out_slots) {
    int orig = blockIdx.x;                 // 704 = 8*88
    int u = (orig & 7) * 88 + (orig >> 3);
    int half = u & 1, bs = u >> 1;
    int b = bs / S, s = bs - b * S;
    int t = threadIdx.x;                   // 0..511
    int wv = t >> 6, l = t & 63, d = l;

    __shared__ float e0s[128], e1s[128], wqs[128];
    __shared__ float rlo0[256], rlo1[256], rn0[128], rn1[128];
    __shared__ float a_l[256], aHp[1024], aHs[128], lgp4[512];
    __shared__ float ul[64], hl[64], gx[192], gh[192];
    __shared__ float xl[64], snl[64], hb[128], xq[64], qs[64], red[12], sc[4];

    // ---- register preloads: data-independent, overlap all phases below ----
    u32 gvp[32];
    {
        int jp = t & 63, q = t >> 6;       // j0 = jp*2 ; n = q*32 + i
        const u32* Gr = (const u32*)(Gv16 + ((size_t)b * 256 + q * 32) * 128) + jp;
        #pragma unroll
        for (int i = 0; i < 32; ++i) gvp[i] = Gr[(size_t)i * 64];
    }
    float gkp[32];
    {
        int n_loc = t & 127, jq = t >> 7;
        const float* Gb = GkT + ((size_t)b * 128 + jq * 32) * 256 + half * 128 + n_loc;
        #pragma unroll
        for (int j = 0; j < 32; ++j) gkp[j] = Gb[(size_t)j * 256];
    }

    if (t < 128) { e0s[t] = ewp[t]; e1s[t] = ewp[128 + t]; }
    if (t < 256) {
        float p0 = sp_r[bs * 2 + 0], p1 = sp_r[bs * 2 + 1];
        float q0 = ss_r[bs * 2 + 0], q1 = ss_r[bs * 2 + 1];
        rlo0[t] = (grid_coord(t >> 4) - p0) / q0;
        rlo1[t] = (grid_coord(t & 15) - p1) / q1;
    }

    // ---- softmax over slots at n = t (t<256) ----
    float a_n = 0.f, g0 = 0.f, g1 = 0.f;
    if (t < 256) {
        float m = -1e30f, lg[S];
        #pragma unroll
        for (int ss2 = 0; ss2 < S; ++ss2) {
            lg[ss2] = lgts_r[((size_t)b * S + ss2) * N + t];
            m = fmaxf(m, lg[ss2]);
        }
        float sum = 0.f, e_own = 0.f;
        #pragma unroll
        for (int ss2 = 0; ss2 < S; ++ss2) {
            float e = expf(lg[ss2] - m);
            sum += e;
            if (ss2 == s) e_own = e;
        }
        a_n = e_own / sum + 1e-8f;
        g0 = grid_coord(t >> 4); g1 = grid_coord(t & 15);
        float sa = a_n, s0 = a_n * g0, s1 = a_n * g1;
        #pragma unroll
        for (int off = 32; off > 0; off >>= 1) {
            sa += __shfl_xor(sa, off);
            s0 += __shfl_xor(s0, off);
            s1 += __shfl_xor(s1, off);
        }
        if (l == 0) { red[wv] = sa; red[4 + wv] = s0; red[8 + wv] = s1; }
    }
    __syncthreads();
    float SA = red[0] + red[1] + red[2] + red[3];
    float wp0 = (red[4] + red[5] + red[6] + red[7]) / SA;
    float wp1 = (red[8] + red[9] + red[10] + red[11]) / SA;
    float inv_sa = 1.0f / SA;
    __syncthreads();
    if (t < 256) {
        float av = a_n * inv_sa + 1e-11f;
        float d0 = g0 - wp0, d1 = g1 - wp1;
        float t0 = d0 * d0 * av, t1 = d1 * d1 * av;
        #pragma unroll
        for (int off = 32; off > 0; off >>= 1) {
            t0 += __shfl_xor(t0, off);
            t1 += __shfl_xor(t1, off);
        }
        if (l == 0) { red[wv] = t0; red[4 + wv] = t1; }
        a_l[t] = a_n * inv_sa;
    }
    __syncthreads();
    float T0c = fminf(fmaxf(sqrtf(red[0] + red[1] + red[2] + red[3]), 0.001f), 5.0f);
    float T1c = fminf(fmaxf(sqrtf(red[4] + red[5] + red[6] + red[7]), 0.001f), 5.0f);

    // ---- aH from preloaded registers: thread = (j-pair, n-octant) ----
    {
        int jp = t & 63, q = t >> 6;
        int j0 = jp * 2;
        float e00 = e0s[j0], e10 = e1s[j0];
        float e01 = e0s[j0 + 1], e11 = e1s[j0 + 1];
        float acc0 = 0.f, acc1 = 0.f;
        #pragma unroll
        for (int i = 0; i < 32; ++i) {
            int n = q * 32 + i;
            float glo = bf2f((u16)(gvp[i] & 0xffffu));
            float ghi = bf2f((u16)(gvp[i] >> 16));
            float r0 = rlo0[n], r1 = rlo1[n], an = a_l[n];
            acc0 += an * fmaxf(glo + r0 * e00 + r1 * e10, 0.f);
            acc1 += an * fmaxf(ghi + r0 * e01 + r1 * e11, 0.f);
        }
        aHp[q * 128 + j0] = acc0;
        aHp[q * 128 + j0 + 1] = acc1;
    }
    __syncthreads();
    if (t < 128) {
        float sj = 0.f;
        #pragma unroll
        for (int q = 0; q < 8; ++q) sj += aHp[q * 128 + t];
        aHs[t] = sj;
    }
    __syncthreads();
    if (t < 64) {
        float u2 = mi_b2[d];
        #pragma unroll 8
        for (int j = 0; j < 128; ++j)
            u2 += aHs[j] * mi_w2[j * 64 + d];
        ul[d] = u2;
        hl[d] = slots_r[bs * D + d];
    }
    __syncthreads();
    if (t < 192) {
        float ax = gru_b[t], ah = gru_b[192 + t];
        #pragma unroll 8
        for (int i = 0; i < 64; ++i) {
            ax += ul[i] * gru_k[i * 192 + t];
            ah += hl[i] * gru_rk[i * 192 + t];
        }
        gx[t] = ax; gh[t] = ah;
    }
    __syncthreads();
    if (t < 64) {
        float z = 1.f / (1.f + expf(-(gx[d] + gh[d])));
        float r = 1.f / (1.f + expf(-(gx[64 + d] + gh[64 + d])));
        float hc = tanhf(gx[128 + d] + r * gh[128 + d]);
        float sn = z * hl[d] + (1.f - z) * hc;
        snl[d] = sn;
        float sm = sn;
        #pragma unroll
        for (int off = 32; off > 0; off >>= 1) sm += __shfl_xor(sm, off);
        float mm = sm * (1.0f / 64.0f);
        float dx = sn - mm;
        float vs = dx * dx;
        #pragma unroll
        for (int off = 32; off > 0; off >>= 1) vs += __shfl_xor(vs, off);
        float var = vs * (1.0f / 64.0f);
        xl[d] = dx * rsqrtf(var + LN_EPS) * nm_g[d] + nm_b[d];
    }
    __syncthreads();
    if (t < 128) {
        float h1 = mlp_b1[t];
        #pragma unroll 8
        for (int i = 0; i < 64; ++i) h1 += xl[i] * mlp_w1[i * 128 + t];
        hb[t] = fmaxf(h1, 0.f);
    }
    __syncthreads();
    if (t < 64) {
        float o = mlp_b2[d];
        #pragma unroll 8
        for (int j = 0; j < 128; ++j) o += hb[j] * mlp_w2[j * D + d];
        float res = snl[d] + o;
        slots_w[bs * D + d] = res;
        if (ind == 2) out_slots[bs * D + d] = res;
        float sm = res;
        #pragma unroll
        for (int off = 32; off > 0; off >>= 1) sm += __shfl_xor(sm, off);
        float mm = sm * (1.0f / 64.0f);
        float dx = res - mm;
        float vs = dx * dx;
        #pragma unroll
        for (int off = 32; off > 0; off >>= 1) vs += __shfl_xor(vs, off);
        float var = vs * (1.0f / 64.0f);
        xq[d] = dx * rsqrtf(var + LN_EPS) * ns_g[d] + ns_b[d];
    }
    __syncthreads();
    if (t < 64) {
        float acc = pq_b[d];
        #pragma unroll 8
        for (int i = 0; i < 64; ++i) acc += xq[i] * pq_w[i * D + d];
        qs[d] = acc * 0.125f;
    }
    __syncthreads();
    {
        float wql = 0.f;
        if (t < 128) {
            #pragma unroll 8
            for (int dd = 0; dd < 64; ++dd) wql += mi_w2[t * 64 + dd] * qs[dd];
        }
        float b2v = 0.f;
        if (t < 64) {
            b2v = mi_b2[d] * qs[d];
            #pragma unroll
            for (int off = 32; off > 0; off >>= 1) b2v += __shfl_xor(b2v, off);
        }
        if (t < 128) wqs[t] = wql;
        if (t == 0) {
            sc[0] = b2v;
            sp_w[bs * 2 + 0] = wp0; sp_w[bs * 2 + 1] = wp1;
            ss_w[bs * 2 + 0] = T0c; ss_w[bs * 2 + 1] = T1c;
        }
        if (t < 128) {
            int n = half * 128 + t;
            rn0[t] = (grid_coord(n >> 4) - wp0) / T0c;
            rn1[t] = (grid_coord(n & 15) - wp1) / T1c;
        }
    }
    __syncthreads();

    // ---- Phase K from preloaded registers: 4 threads per n ----
    {
        int n_loc = t & 127, jq = t >> 7;     // jq in 0..3
        float r0 = rn0[n_loc], r1 = rn1[n_loc];
        float acc = 0.f;
        #pragma unroll
        for (int j = 0; j < 32; ++j) {
            int jj = jq * 32 + j;
            float h = gkp[j] + r0 * e0s[jj] + r1 * e1s[jj];
            acc += fmaxf(h, 0.f) * wqs[jj];
        }
        lgp4[jq * 128 + n_loc] = acc;
        __syncthreads();
        if (t < 128)
            lgts_w[((size_t)b * S + s) * N + half * 128 + t] =
                lgp4[t] + lgp4[128 + t] + lgp4[256 + t] + lgp4[384 + t] + sc[0];
    }
}

// ============ FIN: final softmax/calcSP -> attn_out, osp, oss ===============
__global__ __launch_bounds__(256) void fin_kernel(
    const float* __restrict__ lgts_r,
    float* __restrict__ attn_out, float* __restrict__ osp, float* __restrict__ oss) {
    int orig = blockIdx.x;
    int bs = (orig & 7) * 44 + (orig >> 3);
    int b = bs / S, s = bs - b * S;
    int t = threadIdx.x;
    int wv = t >> 6, l = t & 63;
    __shared__ float red[12];
    float m = -1e30f, lg[S];
    #pragma unroll
    for (int ss2 = 0; ss2 < S; ++ss2) {
        lg[ss2] = lgts_r[((size_t)b * S + ss2) * N + t];
        m = fmaxf(m, lg[ss2]);
    }
    float sum = 0.f, e_own = 0.f;
    #pragma unroll
    for (int ss2 = 0; ss2 < S; ++ss2) {
        float e = expf(lg[ss2] - m);
        sum += e;
        if (ss2 == s) e_own = e;
    }
    float a_n = e_own / sum + 1e-8f;
    float g0 = grid_coord(t >> 4), g1 = grid_coord(t & 15);
    float sa = a_n, s0 = a_n * g0, s1 = a_n * g1;
    #pragma unroll
    for (int off = 32; off > 0; off >>= 1) {
        sa += __shfl_xor(sa, off);
        s0 += __shfl_xor(s0, off);
        s1 += __shfl_xor(s1, off);
    }
    if (l == 0) { red[wv] = sa; red[4 + wv] = s0; red[8 + wv] = s1; }
    __syncthreads();
    float SA = red[0] + red[1] + red[2] + red[3];
    float wp0 = (red[4] + red[5] + red[6] + red[7]) / SA;
    float wp1 = (red[8] + red[9] + red[10] + red[11]) / SA;
    float inv_sa = 1.0f / SA;
    float av = a_n * inv_sa + 1e-11f;
    float d0 = g0 - wp0, d1 = g1 - wp1;
    float t0 = d0 * d0 * av, t1 = d1 * d1 * av;
    #pragma unroll
    for (int off = 32; off > 0; off >>= 1) {
        t0 += __shfl_xor(t0, off);
        t1 += __shfl_xor(t1, off);
    }
    __syncthreads();
    if (l == 0) { red[wv] = t0; red[4 + wv] = t1; }
    __syncthreads();
    if (t == 0) {
        osp[bs * 2 + 0] = wp0;
        osp[bs * 2 + 1] = wp1;
        oss[bs * 2 + 0] = fminf(fmaxf(sqrtf(red[0] + red[1] + red[2] + red[3]), 0.001f), 5.0f);
        oss[bs * 2 + 1] = fminf(fmaxf(sqrtf(red[4] + red[5] + red[6] + red[7]), 0.001f), 5.0f);
    }
    attn_out[((size_t)b * N + t) * S + s] = a_n * inv_sa;
}

extern "C" void kernel_launch(void* const* d_in, const int* in_sizes, int n_in,
                              void* d_out, int out_size, void* d_ws, size_t ws_size,
                              hipStream_t stream) {
    const float* inputs  = (const float*)d_in[0];
    const float* s_p0    = (const float*)d_in[1];
    const float* s_s0    = (const float*)d_in[2];
    const float* slots_mu= (const float*)d_in[3];
    const float* es_w1   = (const float*)d_in[4];
    const float* es_b1   = (const float*)d_in[5];
    const float* es_w2   = (const float*)d_in[6];
    const float* es_b2   = (const float*)d_in[7];
    const float* er_w    = (const float*)d_in[8];
    const float* er_b    = (const float*)d_in[9];
    const float* pk_w    = (const float*)d_in[10];
    const float* pk_b    = (const float*)d_in[11];
    const float* pv_w    = (const float*)d_in[12];
    const float* pv_b    = (const float*)d_in[13];
    const float* pq_w    = (const float*)d_in[14];
    const float* pq_b    = (const float*)d_in[15];
    const float* mi_w1   = (const float*)d_in[16];
    const float* mi_b1   = (const float*)d_in[17];
    const float* mi_w2   = (const float*)d_in[18];
    const float* mi_b2   = (const float*)d_in[19];
    const float* ns_g    = (const float*)d_in[20];
    const float* ns_b    = (const float*)d_in[21];
    const float* nm_g    = (const float*)d_in[22];
    const float* nm_b    = (const float*)d_in[23];
    const float* gru_k   = (const float*)d_in[24];
    const float* gru_rk  = (const float*)d_in[25];
    const float* gru_b   = (const float*)d_in[26];
    const float* mlp_w1  = (const float*)d_in[27];
    const float* mlp_b1  = (const float*)d_in[28];
    const float* mlp_w2  = (const float*)d_in[29];
    const float* mlp_b2  = (const float*)d_in[30];

    float* ws     = (float*)d_ws;
    float* pos    = ws;                        // 131072
    float* GkT    = pos    + 131072;           // 1048576 (fp32, bias folded)
    u16*   Gv16   = (u16*)(GkT + 1048576);     // 2097152 u16
    float* lgts0  = GkT + 2097152;             // 90112
    float* lgts1  = lgts0  + 90112;            // 90112
    float* slots0 = lgts1  + 90112;            // 22528
    float* slots1 = slots0 + 22528;            // 22528
    float* sp0    = slots1 + 22528;            // 704
    float* ss0    = sp0    + 704;              // 704
    float* sp1    = ss0    + 704;              // 704
    float* ss1    = sp1    + 704;              // 704
    float* w2q0   = ss1    + 704;              // 1408
    float* b2q0   = w2q0   + 1408;             // 16
    float* ewp    = b2q0   + 16;               // 512
    u16*   wkT    = (u16*)(ewp + 512);         // 65536 u16 (wvT follows)
    u16*   wvT    = wkT + 65536;               // 65536 u16

    float* out      = (float*)d_out;
    float* out_sp   = out + B * S * D;
    float* out_ss   = out_sp + B * S * 2;
    float* attn_out = out_ss + B * S * 2;

    pre1_kernel<<<869, 256, 0, stream>>>(es_w1, es_b1, es_w2, es_b2,
                                         mi_w1, mi_b1, mi_w2, mi_b2,
                                         pk_w, pk_b, pv_w, pv_b, er_w, er_b,
                                         slots_mu, s_p0, s_s0,
                                         ns_g, ns_b, pq_w, pq_b,
                                         pos, wkT, wvT, ewp,
                                         slots0, sp0, ss0, w2q0, b2q0);
    pre2_kernel<<<512, 256, 0, stream>>>(inputs, pos, wkT, ewp,
                                         s_p0, s_s0, w2q0, b2q0,
                                         GkT, Gv16, lgts0);
    upkv_kernel<<<704, 512, 0, stream>>>(0, lgts0, lgts1, sp0, ss0, sp1, ss1,
                                         slots0, slots1, GkT, Gv16, ewp,
                                         gru_k, gru_rk, gru_b, nm_g, nm_b,
                                         mlp_w1, mlp_b1, mlp_w2, mlp_b2,
                                         ns_g, ns_b, pq_w, pq_b, mi_w2, mi_b2, out);
    upkv_kernel<<<704, 512, 0, stream>>>(1, lgts1, lgts0, sp1, ss1, sp0, ss0,
                                         slots1, slots0, GkT, Gv16, ewp,
                                         gru_k, gru_rk, gru_b, nm_g, nm_b,
                                         mlp_w1, mlp_b1, mlp_w2, mlp_b2,
                                         ns_g, ns_b, pq_w, pq_b, mi_w2, mi_b2, out);
    upkv_kernel<<<704, 512, 0, stream>>>(2, lgts0, lgts1, sp0, ss0, sp1, ss1,
                                         slots0, slots1, GkT, Gv16, ewp,
                                         gru_k, gru_rk, gru_b, nm_g, nm_b,
                                         mlp_w1, mlp_b1, mlp_w2, mlp_b2,
                                         ns_g, ns_b, pq_w, pq_b, mi_w2, mi_b2, out);
    fin_kernel<<<352, 256, 0, stream>>>(lgts1, attn_out, out_sp, out_ss);
}

// Round 17
// 117.545 us; speedup vs baseline: 1.3012x; 1.3012x over previous
//
#include <hip/hip_runtime.h>
#include <cmath>

#define B 32
#define S 11
#define R 16
#define D 64
#define C 512
#define N 256   // R*R
#define LN_EPS 1e-3f

typedef unsigned short u16;
typedef unsigned int   u32;

using bf16x8 = __attribute__((ext_vector_type(8))) short;
using f32x4  = __attribute__((ext_vector_type(4))) float;

__device__ __forceinline__ float grid_coord(int i) {
    return -1.0f + (2.0f / 15.0f) * (float)i;
}

__device__ __forceinline__ u16 f2bf(float x) {
    union { float f; u32 u; } c; c.f = x;
    u32 r = c.u + 0x7fffu + ((c.u >> 16) & 1u);   // RNE
    return (u16)(r >> 16);
}

__device__ __forceinline__ float bf2f(u16 h) {
    union { u32 u; float f; } c; c.u = ((u32)h) << 16; return c.f;
}

// ==== PRE1: pos (0..255) | wprep (256..769) | init (770..857) | q0 (858..868)
__global__ __launch_bounds__(256) void pre1_kernel(
    const float* __restrict__ es_w1, const float* __restrict__ es_b1,
    const float* __restrict__ es_w2, const float* __restrict__ es_b2,
    const float* __restrict__ mi_w1, const float* __restrict__ mi_b1,
    const float* __restrict__ mi_w2, const float* __restrict__ mi_b2,
    const float* __restrict__ pk_w, const float* __restrict__ pk_b,
    const float* __restrict__ pv_w, const float* __restrict__ pv_b,
    const float* __restrict__ er_w, const float* __restrict__ er_b,
    const float* __restrict__ slots_mu, const float* __restrict__ s_p0,
    const float* __restrict__ s_s0,
    const float* __restrict__ ns_g, const float* __restrict__ ns_b,
    const float* __restrict__ pq_w, const float* __restrict__ pq_b,
    float* __restrict__ pos,
    u16* __restrict__ wkT, u16* __restrict__ wvT,
    float* __restrict__ ewp,
    float* __restrict__ slots0, float* __restrict__ sp0, float* __restrict__ ss0,
    float* __restrict__ w2q0, float* __restrict__ b2q0) {
    int bid = blockIdx.x;
    int t = threadIdx.x;
    if (bid < 256) {
        int n = bid;
        float g0 = grid_coord(n >> 4), g1 = grid_coord(n & 15);
        __shared__ float h[128];
        if (t < 128) {
            float hj = es_b1[t] + g0 * es_w1[t] + g1 * es_w1[128 + t];
            h[t] = fmaxf(hj, 0.0f);
        }
        __syncthreads();
        #pragma unroll
        for (int c0 = 0; c0 < C; c0 += 256) {
            int c = c0 + t;
            float acc = es_b2[c];
            #pragma unroll 16
            for (int jj = 0; jj < 128; ++jj) acc += h[jj] * es_w2[jj * C + c];
            pos[n * C + c] = acc;
        }
    } else if (bid < 770) {
        int idx = (bid - 256) * 256 + t;       // 0..131583
        if (idx < 131072) {
            int mat = idx >> 16;
            int i = idx & 65535;
            int c = i >> 7, j = i & 127;
            const float* pw = mat ? pv_w : pk_w;
            float acc = 0.f;
            #pragma unroll 8
            for (int k = 0; k < 64; ++k) acc += pw[c * 64 + k] * mi_w1[k * 128 + j];
            u16* dst = mat ? wvT : wkT;
            dst[j * 512 + c] = f2bf(acc);
        } else {
            int i = idx - 131072;              // 0..511
            int tt = i >> 7, j = i & 127;
            float acc = 0.f;
            if (tt == 0) {
                for (int k = 0; k < 64; ++k) acc += er_w[k] * mi_w1[k * 128 + j];
            } else if (tt == 1) {
                for (int k = 0; k < 64; ++k) acc += er_w[64 + k] * mi_w1[k * 128 + j];
            } else if (tt == 2) {
                for (int k = 0; k < 64; ++k) acc += (pk_b[k] + er_b[k]) * mi_w1[k * 128 + j];
                acc += mi_b1[j];
            } else {
                for (int k = 0; k < 64; ++k) acc += (pv_b[k] + er_b[k]) * mi_w1[k * 128 + j];
                acc += mi_b1[j];
            }
            ewp[i] = acc;
        }
    } else if (bid < 858) {
        int idx = (bid - 770) * 256 + t;
        slots0[idx] = slots_mu[idx % (S * D)];
        if (idx < B * S * 2) { sp0[idx] = s_p0[idx]; ss0[idx] = s_s0[idx]; }
    } else {
        // initial q -> w2q0/b2q0, per distinct slot s (slots identical over b)
        int s = bid - 858;                     // 0..10
        __shared__ float xlds[64], qs2[64];
        if (t < 64) {
            float x = slots_mu[s * D + t];
            float sum = x;
            #pragma unroll
            for (int off = 32; off > 0; off >>= 1) sum += __shfl_xor(sum, off);
            float m = sum * (1.0f / 64.0f);
            float dx = x - m;
            float vs = dx * dx;
            #pragma unroll
            for (int off = 32; off > 0; off >>= 1) vs += __shfl_xor(vs, off);
            float var = vs * (1.0f / 64.0f);
            xlds[t] = dx * rsqrtf(var + LN_EPS) * ns_g[t] + ns_b[t];
        }
        __syncthreads();
        if (t < 64) {
            float acc = pq_b[t];
            #pragma unroll 8
            for (int i = 0; i < 64; ++i) acc += xlds[i] * pq_w[i * D + t];
            qs2[t] = acc * 0.125f;
        }
        __syncthreads();
        if (t < 128) {
            float sacc = 0.f;
            #pragma unroll 8
            for (int dd = 0; dd < 64; ++dd) sacc += mi_w2[t * 64 + dd] * qs2[dd];
            w2q0[s * 128 + t] = sacc;
        }
        if (t < 64) {
            float v = mi_b2[t] * qs2[t];
            #pragma unroll
            for (int off = 32; off > 0; off >>= 1) v += __shfl_xor(v, off);
            if (t == 0) b2q0[s] = v;
        }
    }
}

// ============ PRE2: xw1 + iteration-0 logits (512 blocks) ===================
// GkT[b][j][n] fp32 (bbk folded), Gv16[b][n][j] bf16 (bbv folded), lgts0
__global__ __launch_bounds__(256) void pre2_kernel(
    const float* __restrict__ inputs, const float* __restrict__ pos,
    const u16* __restrict__ wkT,      // wvT at +65536
    const float* __restrict__ ewp,
    const float* __restrict__ s_p0, const float* __restrict__ s_s0,
    const float* __restrict__ w2q0, const float* __restrict__ b2q0,
    float* __restrict__ GkT, u16* __restrict__ Gv16,
    float* __restrict__ lgts0) {
    int bid = blockIdx.x;
    int t = threadIdx.x;
    int row0 = bid * 16;
    __shared__ u16 Xs[16 * 512];
    __shared__ float Gs[16 * 129];
    __shared__ float w2qs[11 * 132];
    __shared__ float e0s[128], e1s[128], bbk2[128], bbv2[128];
    if (t < 128) {
        e0s[t] = ewp[t]; e1s[t] = ewp[128 + t];
        bbk2[t] = ewp[256 + t]; bbv2[t] = ewp[384 + t];
    }
    for (int i = t; i < 11 * 128; i += 256)
        w2qs[(i >> 7) * 132 + (i & 127)] = w2q0[i];

    const float4* in4 = (const float4*)(inputs + (size_t)row0 * C);
    #pragma unroll
    for (int it = 0; it < 8; ++it) {
        int f = it * 256 + t;
        int lr = f >> 7;
        int c = (f & 127) * 4;
        float4 a = in4[f];
        float4 p = *(const float4*)(pos + (size_t)((row0 + lr) & (N - 1)) * C + c);
        u32 lo = (u32)f2bf(a.x + p.x) | ((u32)f2bf(a.y + p.y) << 16);
        u32 hi = (u32)f2bf(a.z + p.z) | ((u32)f2bf(a.w + p.w) << 16);
        int cs = c ^ ((lr & 7) << 3);
        *(uint2*)&Xs[lr * 512 + cs] = make_uint2(lo, hi);
    }
    __syncthreads();

    int w = t >> 6, l = t & 63;
    int l16 = l & 15, lq = l >> 4;
    int wc = w * 32;
    int b = row0 >> 8, nb = row0 & (N - 1);

    f32x4 acc[2][2];
    #pragma unroll
    for (int m = 0; m < 2; ++m)
        #pragma unroll
        for (int nt = 0; nt < 2; ++nt) acc[m][nt] = (f32x4){0.f, 0.f, 0.f, 0.f};

    for (int kt = 0; kt < 16; ++kt) {
        int k0 = kt * 32 + lq * 8;
        int ks = k0 ^ ((l16 & 7) << 3);
        bf16x8 xf = *(const bf16x8*)&Xs[l16 * 512 + ks];
        #pragma unroll
        for (int m = 0; m < 2; ++m) {
            const u16* Wm = wkT + (size_t)m * 65536;
            #pragma unroll
            for (int nt = 0; nt < 2; ++nt) {
                bf16x8 wf = *(const bf16x8*)(Wm + (size_t)(wc + nt * 16 + l16) * 512 + k0);
                acc[m][nt] = __builtin_amdgcn_mfma_f32_16x16x32_bf16(xf, wf, acc[m][nt], 0, 0, 0);
            }
        }
    }
    #pragma unroll
    for (int nt = 0; nt < 2; ++nt) {
        #pragma unroll
        for (int r = 0; r < 4; ++r) {
            int j = wc + nt * 16 + l16;
            int nl = lq * 4 + r;
            int n2 = nb + nl;
            float gk = acc[0][nt][r] + bbk2[j];
            GkT[((size_t)b * 128 + j) * 256 + n2] = gk;
            Gs[nl * 129 + j] = gk;
            Gv16[((size_t)b * 256 + n2) * 128 + j] = f2bf(acc[1][nt][r] + bbv2[j]);
        }
    }
    __syncthreads();

    // iteration-0 logits for this block's 16 n values x 11 slots
    if (t < 176) {
        int nl = t & 15, s = t >> 4;     // s in 0..10
        int n = nb + nl;
        int i2 = (b * S + s) * 2;
        float p0 = s_p0[i2 + 0], p1 = s_p0[i2 + 1];
        float q0 = s_s0[i2 + 0], q1 = s_s0[i2 + 1];
        float r0 = (grid_coord(n >> 4) - p0) / q0;
        float r1 = (grid_coord(n & 15) - p1) / q1;
        float accl = 0.f;
        #pragma unroll 8
        for (int j = 0; j < 128; ++j) {
            float h = Gs[nl * 129 + j] + r0 * e0s[j] + r1 * e1s[j];
            accl += fmaxf(h, 0.f) * w2qs[s * 132 + j];
        }
        lgts0[((size_t)b * S + s) * N + n] = accl + b2q0[s];
    }
}

// ============ UPKV: update(ind) [dup per half] + logits(ind+1), 512 thr =====
__global__ __launch_bounds__(512) void upkv_kernel(
    int ind,
    const float* __restrict__ lgts_r, float* __restrict__ lgts_w,
    const float* __restrict__ sp_r, const float* __restrict__ ss_r,
    float* __restrict__ sp_w, float* __restrict__ ss_w,
    const float* __restrict__ slots_r, float* __restrict__ slots_w,
    const float* __restrict__ GkT, const u16* __restrict__ Gv16,
    const float* __restrict__ ewp,
    const float* __restrict__ gru_k, const float* __restrict__ gru_rk,
    const float* __restrict__ gru_b,
    const float* __restrict__ nm_g, const float* __restrict__ nm_b,
    const float* __restrict__ mlp_w1, const float* __restrict__ mlp_b1,
    const float* __restrict__ mlp_w2, const float* __restrict__ mlp_b2,
    const float* __restrict__ ns_g, const float* __restrict__ ns_b,
    const float* __restrict__ pq_w, const float* __restrict__ pq_b,
    const float* __restrict__ mi_w2, const float* __restrict__ mi_b2,
    float* __restrict__ out_slots) {
    int orig = blockIdx.x;                 // 704 = 8*88
    int u = (orig & 7) * 88 + (orig >> 3);
    int half = u & 1, bs = u >> 1;
    int b = bs / S, s = bs - b * S;
    int t = threadIdx.x;                   // 0..511
    int wv = t >> 6, l = t & 63, d = l;

    __shared__ float e0s[128], e1s[128], wqs[128];
    __shared__ float rlo0[256], rlo1[256], rn0[128], rn1[128];
    __shared__ float a_l[256], aH4[512], lgp4[512];
    __shared__ float ul[64], hl[64], gx[192], gh[192];
    __shared__ float xl[64], snl[64], hb[128], xq[64], qs[64], red[12], sc[4];

    if (t < 128) { e0s[t] = ewp[t]; e1s[t] = ewp[128 + t]; }
    if (t < 256) {
        float p0 = sp_r[bs * 2 + 0], p1 = sp_r[bs * 2 + 1];
        float q0 = ss_r[bs * 2 + 0], q1 = ss_r[bs * 2 + 1];
        rlo0[t] = (grid_coord(t >> 4) - p0) / q0;
        rlo1[t] = (grid_coord(t & 15) - p1) / q1;
    }

    // ---- softmax over slots at n = t (t<256) ----
    float a_n = 0.f, g0 = 0.f, g1 = 0.f;
    if (t < 256) {
        float m = -1e30f, lg[S];
        #pragma unroll
        for (int ss2 = 0; ss2 < S; ++ss2) {
            lg[ss2] = lgts_r[((size_t)b * S + ss2) * N + t];
            m = fmaxf(m, lg[ss2]);
        }
        float sum = 0.f, e_own = 0.f;
        #pragma unroll
        for (int ss2 = 0; ss2 < S; ++ss2) {
            float e = expf(lg[ss2] - m);
            sum += e;
            if (ss2 == s) e_own = e;
        }
        a_n = e_own / sum + 1e-8f;
        g0 = grid_coord(t >> 4); g1 = grid_coord(t & 15);
        float sa = a_n, s0 = a_n * g0, s1 = a_n * g1;
        #pragma unroll
        for (int off = 32; off > 0; off >>= 1) {
            sa += __shfl_xor(sa, off);
            s0 += __shfl_xor(s0, off);
            s1 += __shfl_xor(s1, off);
        }
        if (l == 0) { red[wv] = sa; red[4 + wv] = s0; red[8 + wv] = s1; }
    }
    __syncthreads();
    float SA = red[0] + red[1] + red[2] + red[3];
    float wp0 = (red[4] + red[5] + red[6] + red[7]) / SA;
    float wp1 = (red[8] + red[9] + red[10] + red[11]) / SA;
    float inv_sa = 1.0f / SA;
    __syncthreads();
    if (t < 256) {
        float av = a_n * inv_sa + 1e-11f;
        float d0 = g0 - wp0, d1 = g1 - wp1;
        float t0 = d0 * d0 * av, t1 = d1 * d1 * av;
        #pragma unroll
        for (int off = 32; off > 0; off >>= 1) {
            t0 += __shfl_xor(t0, off);
            t1 += __shfl_xor(t1, off);
        }
        if (l == 0) { red[wv] = t0; red[4 + wv] = t1; }
        a_l[t] = a_n * inv_sa;
    }
    __syncthreads();
    float T0c = fminf(fmaxf(sqrtf(red[0] + red[1] + red[2] + red[3]), 0.001f), 5.0f);
    float T1c = fminf(fmaxf(sqrtf(red[4] + red[5] + red[6] + red[7]), 0.001f), 5.0f);

    // ---- aH: all 512 threads, n split into 4 quarters of 64 ----
    {
        int j = t & 127, q = t >> 7;          // q in 0..3
        const u16* Gr = Gv16 + ((size_t)b * 256 + q * 64) * 128 + j;
        float e0j = e0s[j], e1j = e1s[j];
        float acc = 0.f;
        #pragma unroll 8
        for (int i = 0; i < 64; ++i) {
            int n = q * 64 + i;
            float h = bf2f(Gr[(size_t)i * 128]) + rlo0[n] * e0j + rlo1[n] * e1j;
            acc += a_l[n] * fmaxf(h, 0.f);
        }
        aH4[q * 128 + j] = acc;
    }
    __syncthreads();
    if (t < 64) {
        float u2 = mi_b2[d];
        #pragma unroll 8
        for (int j = 0; j < 128; ++j)
            u2 += (aH4[j] + aH4[128 + j] + aH4[256 + j] + aH4[384 + j]) * mi_w2[j * 64 + d];
        ul[d] = u2;
        hl[d] = slots_r[bs * D + d];
    }
    __syncthreads();
    if (t < 192) {
        float ax = gru_b[t], ah = gru_b[192 + t];
        #pragma unroll 8
        for (int i = 0; i < 64; ++i) {
            ax += ul[i] * gru_k[i * 192 + t];
            ah += hl[i] * gru_rk[i * 192 + t];
        }
        gx[t] = ax; gh[t] = ah;
    }
    __syncthreads();
    if (t < 64) {
        float z = 1.f / (1.f + expf(-(gx[d] + gh[d])));
        float r = 1.f / (1.f + expf(-(gx[64 + d] + gh[64 + d])));
        float hc = tanhf(gx[128 + d] + r * gh[128 + d]);
        float sn = z * hl[d] + (1.f - z) * hc;
        snl[d] = sn;
        float sm = sn;
        #pragma unroll
        for (int off = 32; off > 0; off >>= 1) sm += __shfl_xor(sm, off);
        float mm = sm * (1.0f / 64.0f);
        float dx = sn - mm;
        float vs = dx * dx;
        #pragma unroll
        for (int off = 32; off > 0; off >>= 1) vs += __shfl_xor(vs, off);
        float var = vs * (1.0f / 64.0f);
        xl[d] = dx * rsqrtf(var + LN_EPS) * nm_g[d] + nm_b[d];
    }
    __syncthreads();
    if (t < 128) {
        float h1 = mlp_b1[t];
        #pragma unroll 8
        for (int i = 0; i < 64; ++i) h1 += xl[i] * mlp_w1[i * 128 + t];
        hb[t] = fmaxf(h1, 0.f);
    }
    __syncthreads();
    if (t < 64) {
        float o = mlp_b2[d];
        #pragma unroll 8
        for (int j = 0; j < 128; ++j) o += hb[j] * mlp_w2[j * D + d];
        float res = snl[d] + o;
        slots_w[bs * D + d] = res;
        if (ind == 2) out_slots[bs * D + d] = res;
        float sm = res;
        #pragma unroll
        for (int off = 32; off > 0; off >>= 1) sm += __shfl_xor(sm, off);
        float mm = sm * (1.0f / 64.0f);
        float dx = res - mm;
        float vs = dx * dx;
        #pragma unroll
        for (int off = 32; off > 0; off >>= 1) vs += __shfl_xor(vs, off);
        float var = vs * (1.0f / 64.0f);
        xq[d] = dx * rsqrtf(var + LN_EPS) * ns_g[d] + ns_b[d];
    }
    __syncthreads();
    if (t < 64) {
        float acc = pq_b[d];
        #pragma unroll 8
        for (int i = 0; i < 64; ++i) acc += xq[i] * pq_w[i * D + d];
        qs[d] = acc * 0.125f;
    }
    __syncthreads();
    {
        float wql = 0.f;
        if (t < 128) {
            #pragma unroll 8
            for (int dd = 0; dd < 64; ++dd) wql += mi_w2[t * 64 + dd] * qs[dd];
        }
        float b2v = 0.f;
        if (t < 64) {
            b2v = mi_b2[d] * qs[d];
            #pragma unroll
            for (int off = 32; off > 0; off >>= 1) b2v += __shfl_xor(b2v, off);
        }
        if (t < 128) wqs[t] = wql;
        if (t == 0) {
            sc[0] = b2v;
            sp_w[bs * 2 + 0] = wp0; sp_w[bs * 2 + 1] = wp1;
            ss_w[bs * 2 + 0] = T0c; ss_w[bs * 2 + 1] = T1c;
        }
        if (t < 128) {
            int n = half * 128 + t;
            rn0[t] = (grid_coord(n >> 4) - wp0) / T0c;
            rn1[t] = (grid_coord(n & 15) - wp1) / T1c;
        }
    }
    __syncthreads();

    // ---- Phase K: logits(ind+1) for own half; 4 threads per n ----
    {
        int n_loc = t & 127, jq = t >> 7;     // jq in 0..3
        float r0 = rn0[n_loc], r1 = rn1[n_loc];
        const float* Gb = GkT + ((size_t)b * 128 + jq * 32) * 256 + half * 128 + n_loc;
        float acc = 0.f;
        #pragma unroll 8
        for (int j = 0; j < 32; ++j) {
            int jj = jq * 32 + j;
            float h = Gb[(size_t)j * 256] + r0 * e0s[jj] + r1 * e1s[jj];
            acc += fmaxf(h, 0.f) * wqs[jj];
        }
        lgp4[jq * 128 + n_loc] = acc;
        __syncthreads();
        if (t < 128)
            lgts_w[((size_t)b * S + s) * N + half * 128 + t] =
                lgp4[t] + lgp4[128 + t] + lgp4[256 + t] + lgp4[384 + t] + sc[0];
    }
}

// ============ FIN: final softmax/calcSP -> attn_out, osp, oss ===============
__global__ __launch_bounds__(256) void fin_kernel(
    const float* __restrict__ lgts_r,
    float* __restrict__ attn_out, float* __restrict__ osp, float* __restrict__ oss) {
    int orig = blockIdx.x;
    int bs = (orig & 7) * 44 + (orig >> 3);
    int b = bs / S, s = bs - b * S;
    int t = threadIdx.x;
    int wv = t >> 6, l = t & 63;
    __shared__ float red[12];
    float m = -1e30f, lg[S];
    #pragma unroll
    for (int ss2 = 0; ss2 < S; ++ss2) {
        lg[ss2] = lgts_r[((size_t)b * S + ss2) * N + t];
        m = fmaxf(m, lg[ss2]);
    }
    float sum = 0.f, e_own = 0.f;
    #pragma unroll
    for (int ss2 = 0; ss2 < S; ++ss2) {
        float e = expf(lg[ss2] - m);
        sum += e;
        if (ss2 == s) e_own = e;
    }
    float a_n = e_own / sum + 1e-8f;
    float g0 = grid_coord(t >> 4), g1 = grid_coord(t & 15);
    float sa = a_n, s0 = a_n * g0, s1 = a_n * g1;
    #pragma unroll
    for (int off = 32; off > 0; off >>= 1) {
        sa += __shfl_xor(sa, off);
        s0 += __shfl_xor(s0, off);
        s1 += __shfl_xor(s1, off);
    }
    if (l == 0) { red[wv] = sa; red[4 + wv] = s0; red[8 + wv] = s1; }
    __syncthreads();
    float SA = red[0] + red[1] + red[2] + red[3];
    float wp0 = (red[4] + red[5] + red[6] + red[7]) / SA;
    float wp1 = (red[8] + red[9] + red[10] + red[11]) / SA;
    float inv_sa = 1.0f / SA;
    float av = a_n * inv_sa + 1e-11f;
    float d0 = g0 - wp0, d1 = g1 - wp1;
    float t0 = d0 * d0 * av, t1 = d1 * d1 * av;
    #pragma unroll
    for (int off = 32; off > 0; off >>= 1) {
        t0 += __shfl_xor(t0, off);
        t1 += __shfl_xor(t1, off);
    }
    __syncthreads();
    if (l == 0) { red[wv] = t0; red[4 + wv] = t1; }
    __syncthreads();
    if (t == 0) {
        osp[bs * 2 + 0] = wp0;
        osp[bs * 2 + 1] = wp1;
        oss[bs * 2 + 0] = fminf(fmaxf(sqrtf(red[0] + red[1] + red[2] + red[3]), 0.001f), 5.0f);
        oss[bs * 2 + 1] = fminf(fmaxf(sqrtf(red[4] + red[5] + red[6] + red[7]), 0.001f), 5.0f);
    }
    attn_out[((size_t)b * N + t) * S + s] = a_n * inv_sa;
}

extern "C" void kernel_launch(void* const* d_in, const int* in_sizes, int n_in,
                              void* d_out, int out_size, void* d_ws, size_t ws_size,
                              hipStream_t stream) {
    const float* inputs  = (const float*)d_in[0];
    const float* s_p0    = (const float*)d_in[1];
    const float* s_s0    = (const float*)d_in[2];
    const float* slots_mu= (const float*)d_in[3];
    const float* es_w1   = (const float*)d_in[4];
    const float* es_b1   = (const float*)d_in[5];
    const float* es_w2   = (const float*)d_in[6];
    const float* es_b2   = (const float*)d_in[7];
    const float* er_w    = (const float*)d_in[8];
    const float* er_b    = (const float*)d_in[9];
    const float* pk_w    = (const float*)d_in[10];
    const float* pk_b    = (const float*)d_in[11];
    const float* pv_w    = (const float*)d_in[12];
    const float* pv_b    = (const float*)d_in[13];
    const float* pq_w    = (const float*)d_in[14];
    const float* pq_b    = (const float*)d_in[15];
    const float* mi_w1   = (const float*)d_in[16];
    const float* mi_b1   = (const float*)d_in[17];
    const float* mi_w2   = (const float*)d_in[18];
    const float* mi_b2   = (const float*)d_in[19];
    const float* ns_g    = (const float*)d_in[20];
    const float* ns_b    = (const float*)d_in[21];
    const float* nm_g    = (const float*)d_in[22];
    const float* nm_b    = (const float*)d_in[23];
    const float* gru_k   = (const float*)d_in[24];
    const float* gru_rk  = (const float*)d_in[25];
    const float* gru_b   = (const float*)d_in[26];
    const float* mlp_w1  = (const float*)d_in[27];
    const float* mlp_b1  = (const float*)d_in[28];
    const float* mlp_w2  = (const float*)d_in[29];
    const float* mlp_b2  = (const float*)d_in[30];

    float* ws     = (float*)d_ws;
    float* pos    = ws;                        // 131072
    float* GkT    = pos    + 131072;           // 1048576 (fp32, bias folded)
    u16*   Gv16   = (u16*)(GkT + 1048576);     // 2097152 u16
    float* lgts0  = GkT + 2097152;             // 90112
    float* lgts1  = lgts0  + 90112;            // 90112
    float* slots0 = lgts1  + 90112;            // 22528
    float* slots1 = slots0 + 22528;            // 22528
    float* sp0    = slots1 + 22528;            // 704
    float* ss0    = sp0    + 704;              // 704
    float* sp1    = ss0    + 704;              // 704
    float* ss1    = sp1    + 704;              // 704
    float* w2q0   = ss1    + 704;              // 1408
    float* b2q0   = w2q0   + 1408;             // 16
    float* ewp    = b2q0   + 16;               // 512
    u16*   wkT    = (u16*)(ewp + 512);         // 65536 u16 (wvT follows)
    u16*   wvT    = wkT + 65536;               // 65536 u16

    float* out      = (float*)d_out;
    float* out_sp   = out + B * S * D;
    float* out_ss   = out_sp + B * S * 2;
    float* attn_out = out_ss + B * S * 2;

    pre1_kernel<<<869, 256, 0, stream>>>(es_w1, es_b1, es_w2, es_b2,
                                         mi_w1, mi_b1, mi_w2, mi_b2,
                                         pk_w, pk_b, pv_w, pv_b, er_w, er_b,
                                         slots_mu, s_p0, s_s0,
                                         ns_g, ns_b, pq_w, pq_b,
                                         pos, wkT, wvT, ewp,
                                         slots0, sp0, ss0, w2q0, b2q0);
    pre2_kernel<<<512, 256, 0, stream>>>(inputs, pos, wkT, ewp,
                                         s_p0, s_s0, w2q0, b2q0,
                                         GkT, Gv16, lgts0);
    upkv_kernel<<<704, 512, 0, stream>>>(0, lgts0, lgts1, sp0, ss0, sp1, ss1,
                                         slots0, slots1, GkT, Gv16, ewp,
                                         gru_k, gru_rk, gru_b, nm_g, nm_b,
                                         mlp_w1, mlp_b1, mlp_w2, mlp_b2,
                                         ns_g, ns_b, pq_w, pq_b, mi_w2, mi_b2, out);
    upkv_kernel<<<704, 512, 0, stream>>>(1, lgts1, lgts0, sp1, ss1, sp0, ss0,
                                         slots1, slots0, GkT, Gv16, ewp,
                                         gru_k, gru_rk, gru_b, nm_g, nm_b,
                                         mlp_w1, mlp_b1, mlp_w2, mlp_b2,
                                         ns_g, ns_b, pq_w, pq_b, mi_w2, mi_b2, out);
    upkv_kernel<<<704, 512, 0, stream>>>(2, lgts0, lgts1, sp0, ss0, sp1, ss1,
                                         slots0, slots1, GkT, Gv16, ewp,
                                         gru_k, gru_rk, gru_b, nm_g, nm_b,
                                         mlp_w1, mlp_b1, mlp_w2, mlp_b2,
                                         ns_g, ns_b, pq_w, pq_b, mi_w2, mi_b2, out);
    fin_kernel<<<352, 256, 0, stream>>>(lgts1, attn_out, out_sp, out_ss);
}